// Round 9
// baseline (58.208 us; speedup 1.0000x reference)
//
#include <hip/hip_runtime.h>
#include <math.h>

// QuantumNATHybridModel: pool(6x6) -> linear(16->4) -> 4-qubit circuit -> BatchNorm1d
// out[b,q] = r^T A_q r; A_q fixed 16x16 from qparams, r from per-sample RX angles.
// R8 lesson: read BW pinned at ~2.9 TB/s (= m13 copy's read component) across all
// load paths. R9: sample-interleaved sweep — at step i the whole chip reads one
// 18 MB moving window (HBM row-locality hypothesis). Otherwise identical to R8.

#define BATCH 65536
#define SPW 8                             // samples per wave (sweep steps)
#define MAIN_BLOCKS (BATCH / (4 * SPW))   // 2048 blocks of 256 threads
#define NWAVES (MAIN_BLOCKS * 4)          // 8192 waves = sweep stride

typedef float vf4 __attribute__((ext_vector_type(4)));

// ---------------------------------------------------------------------------
// Precompute: build U (16x16 complex) from qparams, then A_q (4x16x16 real).
// Also zeroes the 8-double stats accumulator.
// ---------------------------------------------------------------------------
__global__ __launch_bounds__(256) void qnat_precompute(const float* __restrict__ qp,
                                                       float* __restrict__ A,
                                                       double* __restrict__ acc) {
  __shared__ float Ur[16][17], Ui[16][17];
  const int tid = threadIdx.x;
  if (tid >= 64 && tid < 72) acc[tid - 64] = 0.0;
  if (tid < 16) {
    const int col = tid;
    float ur[16], ui[16];
#pragma unroll
    for (int i = 0; i < 16; i++) { ur[i] = (i == col) ? 1.f : 0.f; ui[i] = 0.f; }
#pragma unroll
    for (int l = 0; l < 3; l++) {
#pragma unroll
      for (int q = 0; q < 4; q++) {
        const int b = 3 - q;  // qubit q lives on bit (3-q)
        const float ty = qp[(l * 4 + q) * 3 + 0];
        const float tz = qp[(l * 4 + q) * 3 + 1];
        const float cy = cosf(0.5f * ty), sy = sinf(0.5f * ty);
#pragma unroll
        for (int i0 = 0; i0 < 16; i0++) {
          if (((i0 >> b) & 1) == 0) {
            const int i1 = i0 | (1 << b);
            const float r0 = ur[i0], m0 = ui[i0], r1 = ur[i1], m1 = ui[i1];
            ur[i0] = cy * r0 - sy * r1;  ui[i0] = cy * m0 - sy * m1;
            ur[i1] = sy * r0 + cy * r1;  ui[i1] = sy * m0 + cy * m1;
          }
        }
        const float cz = cosf(0.5f * tz), sz = sinf(0.5f * tz);
#pragma unroll
        for (int i0 = 0; i0 < 16; i0++) {
          if (((i0 >> b) & 1) == 0) {
            const int i1 = i0 | (1 << b);
            const float r0 = ur[i0], m0 = ui[i0], r1 = ur[i1], m1 = ui[i1];
            ur[i0] = cz * r0 + sz * m0;  ui[i0] = cz * m0 - sz * r0;
            ur[i1] = cz * r1 - sz * m1;  ui[i1] = cz * m1 + sz * r1;
          }
        }
      }
      const int cb[4] = {3, 2, 1, 0};
      const int tb[4] = {2, 1, 0, 3};
#pragma unroll
      for (int e = 0; e < 4; e++) {
#pragma unroll
        for (int i = 0; i < 16; i++) {
          if (((i >> cb[e]) & 1) && (((i >> tb[e]) & 1) == 0)) {
            const int j2 = i | (1 << tb[e]);
            float t0 = ur[i]; ur[i] = ur[j2]; ur[j2] = t0;
            float t1 = ui[i]; ui[i] = ui[j2]; ui[j2] = t1;
          }
        }
      }
    }
#pragma unroll
    for (int i = 0; i < 16; i++) { Ur[i][col] = ur[i]; Ui[i][col] = ui[i]; }
  }
  __syncthreads();
  const int j = tid >> 4, k = tid & 15;
#pragma unroll
  for (int q = 0; q < 4; q++) {
    const int b = 3 - q;
    float mr = 0.f, mi = 0.f;
#pragma unroll
    for (int i = 0; i < 16; i++) {
      const float z = ((i >> b) & 1) ? -1.f : 1.f;
      const float ar = Ur[i][j], ai = Ui[i][j], br = Ur[i][k], bi = Ui[i][k];
      mr += z * (ar * br + ai * bi);
      mi += z * (ar * bi - ai * br);
    }
    const int e = (__popc((unsigned)j) - __popc((unsigned)k)) & 3;
    A[(q << 8) + tid] = (e == 0) ? mr : (e == 1) ? -mi : (e == 2) ? -mr : mi;
  }
}

// ---------------------------------------------------------------------------
// Main kernel: sample-interleaved sweep (stride NWAVES), rolling 1-deep prefetch.
// ---------------------------------------------------------------------------
__global__ __launch_bounds__(256, 4) void qnat_main(const float* __restrict__ x,
                                                    const float* __restrict__ enc_w,
                                                    const float* __restrict__ enc_b,
                                                    const float* __restrict__ A,
                                                    float* __restrict__ out,
                                                    double* __restrict__ acc) {
  __shared__ vf4 sW4[16];
  __shared__ double sAcc[4][4][2];   // [wave][q][{sum,sumsq}]
  const int tid = threadIdx.x;
  if (tid < 16) {
    const float inv36 = 1.0f / 36.0f;
    sW4[tid] = (vf4){enc_w[tid] * inv36, enc_w[16 + tid] * inv36,
                     enc_w[32 + tid] * inv36, enc_w[48 + tid] * inv36};
  }
  __syncthreads();

  const int wave = tid >> 6, lane = tid & 63;
  const int j = lane & 15;        // row of A within 16-lane group
  const int g = lane >> 4;        // which qubit's A this group owns
  const bool bit0 = lane & 1, bit1 = lane & 2;

  // Paired pool-weight LDS indices (6-col cell boundary splits any float4 2+2).
  int iX[3], iY[3];
#pragma unroll
  for (int t = 0; t < 3; t++) {
    int p0 = t * 256 + 4 * lane;
    if (p0 > 572) p0 = 572;
    const int row = p0 / 24, col = p0 - row * 24;
    const int rr = (row / 6) * 4;
    iX[t] = rr + col / 6;
    iY[t] = rr + (col + 3) / 6;
  }
  float Areg[16];
#pragma unroll
  for (int k = 0; k < 16; k++) Areg[k] = A[(g << 8) + (j << 4) + k];
  const float bq = enc_b[lane & 3];

  // Sweep: wave wg processes samples {wg, wg+NWAVES, ..., wg+7*NWAVES}.
  const int wg = blockIdx.x * 4 + wave;
  double sd = 0.0, ssd = 0.0;

  auto LOADB = [&](vf4& V0, vf4& V1, vf4& V2, int S) {
    const vf4* p4 = (const vf4*)(x + (size_t)S * 576);
    V0 = p4[lane];
    V1 = p4[64 + lane];
    V2 = (lane < 16) ? p4[128 + lane] : (vf4){0.f, 0.f, 0.f, 0.f};
  };

  auto COMPUTE = [&](const vf4& V0, const vf4& V1, const vf4& V2, int s) {
    float a0 = 0.f, a1 = 0.f, a2 = 0.f, a3 = 0.f;
#define ACCT(V, T)                                           \
    {                                                        \
      const vf4 wX = sW4[iX[T]], wY = sW4[iY[T]];            \
      const float h0 = V[0] + V[1], h1 = V[2] + V[3];        \
      a0 = fmaf(h0, wX[0], fmaf(h1, wY[0], a0));             \
      a1 = fmaf(h0, wX[1], fmaf(h1, wY[1], a1));             \
      a2 = fmaf(h0, wX[2], fmaf(h1, wY[2], a2));             \
      a3 = fmaf(h0, wX[3], fmaf(h1, wY[3], a3));             \
    }
    ACCT(V0, 0) ACCT(V1, 1) ACCT(V2, 2)
#undef ACCT

    // Rotation fold: distribute the 4 angle sums across lane&3 while reducing.
    float snd, rcv;
    snd = bit0 ? a0 : a1; rcv = __shfl_xor(snd, 1);
    float Af = (bit0 ? a1 : a0) + rcv;
    snd = bit0 ? a2 : a3; rcv = __shfl_xor(snd, 1);
    float Bf = (bit0 ? a3 : a2) + rcv;
    snd = bit1 ? Af : Bf; rcv = __shfl_xor(snd, 2);
    float Cf = (bit1 ? Bf : Af) + rcv;
    Cf += __shfl_xor(Cf, 4);
    Cf += __shfl_xor(Cf, 8);
    Cf += __shfl_xor(Cf, 16);
    Cf += __shfl_xor(Cf, 32);                    // theta_{lane&3}

    float sm, cm;
    __sincosf(0.5f * (Cf + bq), &sm, &cm);       // one sincos per lane

    const int base = lane & ~3;
    const float c0 = __shfl(cm, base + 0), s0_ = __shfl(sm, base + 0);
    const float c1 = __shfl(cm, base + 1), s1_ = __shfl(sm, base + 1);
    const float c2 = __shfl(cm, base + 2), s2_ = __shfl(sm, base + 2);
    const float c3 = __shfl(cm, base + 3), s3_ = __shfl(sm, base + 3);

    const float p01[4] = {c0 * c1, c0 * s1_, s0_ * c1, s0_ * s1_};
    const float p23[4] = {c2 * c3, c2 * s3_, s2_ * c3, s2_ * s3_};
    float inner = 0.f;
#pragma unroll
    for (int hi = 0; hi < 4; hi++) {
      float sh = 0.f;
#pragma unroll
      for (int lo = 0; lo < 4; lo++) sh = fmaf(Areg[4 * hi + lo], p23[lo], sh);
      inner = fmaf(p01[hi], sh, inner);
    }
    const float rj = ((j & 8) ? s0_ : c0) * ((j & 4) ? s1_ : c1) *
                     ((j & 2) ? s2_ : c2) * ((j & 1) ? s3_ : c3);
    float v = inner * rj;
    v += __shfl_xor(v, 1);
    v += __shfl_xor(v, 2);
    v += __shfl_xor(v, 4);
    v += __shfl_xor(v, 8);
    if (j == 0) {
      out[(size_t)s * 4 + g] = v;
      sd += (double)v;
      ssd = fma((double)v, (double)v, ssd);
    }
  };

  // Rolling 1-deep pipeline over the sweep, statically named buffers.
  vf4 A0, A1, A2, B0, B1, B2;
  LOADB(A0, A1, A2, wg + 0 * NWAVES);
  LOADB(B0, B1, B2, wg + 1 * NWAVES); COMPUTE(A0, A1, A2, wg + 0 * NWAVES);
  LOADB(A0, A1, A2, wg + 2 * NWAVES); COMPUTE(B0, B1, B2, wg + 1 * NWAVES);
  LOADB(B0, B1, B2, wg + 3 * NWAVES); COMPUTE(A0, A1, A2, wg + 2 * NWAVES);
  LOADB(A0, A1, A2, wg + 4 * NWAVES); COMPUTE(B0, B1, B2, wg + 3 * NWAVES);
  LOADB(B0, B1, B2, wg + 5 * NWAVES); COMPUTE(A0, A1, A2, wg + 4 * NWAVES);
  LOADB(A0, A1, A2, wg + 6 * NWAVES); COMPUTE(B0, B1, B2, wg + 5 * NWAVES);
  LOADB(B0, B1, B2, wg + 7 * NWAVES); COMPUTE(A0, A1, A2, wg + 6 * NWAVES);
  COMPUTE(B0, B1, B2, wg + 7 * NWAVES);

  if (j == 0) { sAcc[wave][g][0] = sd; sAcc[wave][g][1] = ssd; }
  __syncthreads();
  if (tid < 8) {  // tid = m*4 + q
    const int q = tid & 3, m = tid >> 2;
    const double t = sAcc[0][q][m] + sAcc[1][q][m] + sAcc[2][q][m] + sAcc[3][q][m];
    atomicAdd(&acc[m * 4 + q], t);
  }
}

// ---------------------------------------------------------------------------
// Normalize in place: out = (raw - mean)/sqrt(var+eps)*gamma + beta
// ---------------------------------------------------------------------------
__global__ __launch_bounds__(256) void qnat_norm(float* __restrict__ out,
                                                 const double* __restrict__ acc,
                                                 const float* __restrict__ gamma,
                                                 const float* __restrict__ beta) {
  __shared__ float sMean[4], sScale[4], sBeta[4];
  const int tid = threadIdx.x;
  if (tid < 4) {
    const double n = (double)BATCH;
    const double mean = acc[tid] / n;
    const double var = acc[4 + tid] / n - mean * mean;
    const double inv = 1.0 / sqrt(var + 1e-5);
    sMean[tid] = (float)mean;
    sScale[tid] = (float)(gamma[tid] * inv);
    sBeta[tid] = beta[tid];
  }
  __syncthreads();
  const size_t i = (size_t)blockIdx.x * 256 + tid;  // 65536 float4s, 256 blocks
  float4 v = ((const float4*)out)[i];
  v.x = (v.x - sMean[0]) * sScale[0] + sBeta[0];
  v.y = (v.y - sMean[1]) * sScale[1] + sBeta[1];
  v.z = (v.z - sMean[2]) * sScale[2] + sBeta[2];
  v.w = (v.w - sMean[3]) * sScale[3] + sBeta[3];
  ((float4*)out)[i] = v;
}

extern "C" void kernel_launch(void* const* d_in, const int* in_sizes, int n_in,
                              void* d_out, int out_size, void* d_ws, size_t ws_size,
                              hipStream_t stream) {
  const float* x       = (const float*)d_in[0];
  const float* enc_w   = (const float*)d_in[1];
  const float* enc_b   = (const float*)d_in[2];
  const float* qparams = (const float*)d_in[3];
  const float* gamma   = (const float*)d_in[4];
  const float* beta    = (const float*)d_in[5];
  float* out = (float*)d_out;

  float* A = (float*)d_ws;                          // 4*16*16 floats = 4 KB
  double* acc = (double*)((char*)d_ws + 4096);      // 8 doubles

  qnat_precompute<<<1, 256, 0, stream>>>(qparams, A, acc);
  qnat_main<<<MAIN_BLOCKS, 256, 0, stream>>>(x, enc_w, enc_b, A, out, acc);
  qnat_norm<<<256, 256, 0, stream>>>(out, acc, gamma, beta);
}